// Round 12
// baseline (180.825 us; speedup 1.0000x reference)
//
#include <hip/hip_runtime.h>

#define Bsz 4
#define Cch 256
#define Nsp 4096
#define XT_STRIDE 264   // proj LDS stride (halves)

typedef _Float16 half8 __attribute__((ext_vector_type(8)));
typedef _Float16 half4v __attribute__((ext_vector_type(4)));
typedef short short8_t __attribute__((ext_vector_type(8)));
typedef float f32x4 __attribute__((ext_vector_type(4)));
typedef float fl4 __attribute__((ext_vector_type(4)));
typedef unsigned short ushort4v __attribute__((ext_vector_type(4)));

#define LOG2E 1.4426950408889634f
#define NSHIFT (-28.853900817779268f)   // -20 * log2(e)

static __device__ __forceinline__ unsigned short f2bf(float f) {
  unsigned u = __builtin_bit_cast(unsigned, f);
  u += 0x7FFFu + ((u >> 16) & 1u);      // RTNE
  return (unsigned short)(u >> 16);
}

// ---------------- W/bias pre-convert: wq|wk|wv -> Wh f16 [320][256], bias f32 [320]
__global__ __launch_bounds__(256) void wconv_kernel(
    const float* __restrict__ wq, const float* __restrict__ wk, const float* __restrict__ wv,
    const float* __restrict__ bq, const float* __restrict__ bk, const float* __restrict__ bv,
    _Float16* __restrict__ Wh, float* __restrict__ bias)
{
  int t = blockIdx.x * 256 + threadIdx.x;
  int idx0 = t * 4;
  int o = idx0 >> 8, c = idx0 & 255;
  const float* src = (o < 32) ? (wq + o * 256)
                   : (o < 64) ? (wk + (o - 32) * 256)
                              : (wv + (o - 64) * 256);
  fl4 w4 = *(const fl4*)(src + c);
  half4v h;
#pragma unroll
  for (int j = 0; j < 4; ++j) h[j] = (_Float16)w4[j];
  *(half4v*)(Wh + idx0) = h;
  if (t < 320) bias[t] = (t < 32) ? bq[t] : (t < 64) ? bk[t - 32] : bv[t - 64];
}

// ---------------- Projection GEMM: out[o, n] = Wh[o,:] . x[b,:,n] + bias
// Staging now coalesced: each 8-lane group reads a 128-B contiguous n-run.
__global__ __launch_bounds__(256) void proj_kernel(
    const float* __restrict__ x, const _Float16* __restrict__ Wh,
    const float* __restrict__ bias,
    _Float16* __restrict__ qh, _Float16* __restrict__ kh,
    unsigned short* __restrict__ vbuf)
{
  int bid = blockIdx.x;          // 512 = b(4) x nt(128)
  int nt  = bid & 127;
  int b   = bid >> 7;
  int n0  = nt * 32;
  int tid = threadIdx.x;
  int w   = tid >> 6, lane = tid & 63;
  int l15 = lane & 15, lg = lane >> 4;

  __shared__ __align__(16) _Float16 xT[32 * XT_STRIDE];

  const float* xb = x + (size_t)b * Cch * Nsp + n0;

  // stage x[b][:][n0..n0+32) -> xT[n][c] f16: thread reads float4 along n (coalesced
  // in groups of 8 lanes = 128 B), writes 4 scalar f16 to LDS rows.
  {
    int cq = tid >> 3;          // 0..31 within pass
    int nq = (tid & 7) * 4;     // n quad
#pragma unroll
    for (int p = 0; p < 8; ++p) {
      int c = p * 32 + cq;
      fl4 v = *(const fl4*)(xb + (size_t)c * Nsp + nq);
#pragma unroll
      for (int i = 0; i < 4; ++i)
        xT[(nq + i) * XT_STRIDE + c] = (_Float16)v[i];
    }
  }
  __syncthreads();

  int nsub = (w & 1) * 16;
  half8 bX[8];
#pragma unroll
  for (int k = 0; k < 8; ++k)
    bX[k] = *(const half8*)&xT[(nsub + l15) * XT_STRIDE + k * 32 + lg * 8];

  int n = n0 + nsub + l15;
  int ot0 = (w >> 1) * 10;
#pragma unroll
  for (int t = 0; t < 10; ++t) {
    int ot = ot0 + t;
    const _Float16* wrow = Wh + (size_t)(ot * 16 + l15) * 256 + lg * 8;
    f32x4 acc; acc[0]=0.f; acc[1]=0.f; acc[2]=0.f; acc[3]=0.f;
#pragma unroll
    for (int k = 0; k < 8; ++k) {
      half8 aW = *(const half8*)(wrow + k * 32);
      acc = __builtin_amdgcn_mfma_f32_16x16x32_f16(aW, bX[k], acc, 0, 0, 0);
    }
    fl4 bs = *(const fl4*)(bias + ot * 16 + lg * 4);
    if (ot < 2) {
      half4v qv;
#pragma unroll
      for (int r = 0; r < 4; ++r) qv[r] = (_Float16)(acc[r] + bs[r]);
      *(half4v*)(qh + ((size_t)b * Nsp + n) * 32 + ot * 16 + lg * 4) = qv;
    } else if (ot < 4) {
      half4v kv;
#pragma unroll
      for (int r = 0; r < 4; ++r) kv[r] = (_Float16)(acc[r] + bs[r]);
      *(half4v*)(kh + ((size_t)b * Nsp + n) * 32 + (ot - 2) * 16 + lg * 4) = kv;
    } else {
      int cv = (ot - 4) * 16 + lg * 4;
#pragma unroll
      for (int r = 0; r < 4; ++r)
        vbuf[((size_t)b * Cch + cv + r) * Nsp + n] = f2bf(acc[r] + bs[r]);
    }
  }
}

// ---------------- Fused attention: 512 blocks x 1024 thr (16 waves), 2 blocks/CU.
// m-tile 32, n-step 256, 16 iters. QK: wave w owns n-slice [n0+16w,+16) x m32
// (2 MFMA). PV: wave (wk=w>>3, wc=w&7): c-stripe 32*wc, n-half 128*wk (8 MFMA).
// 8 waves/SIMD (2 co-resident blocks) hides V/L2 + barrier latency via TLP —
// the compiler's hard 64-VGPR budget (r6-r10) forbids register prefetch, so
// latency hiding must come from waves. Live state ~48 VGPR (r11-proven).
__global__ __launch_bounds__(1024) void attn_kernel(
    const _Float16* __restrict__ qh, const _Float16* __restrict__ kh,
    const unsigned short* __restrict__ vb, const float* __restrict__ x,
    const float* __restrict__ gamma, float* __restrict__ out)
{
  int bid  = blockIdx.x;                 // 512 blocks
  int xcd  = bid & 7;                    // batch b -> XCDs {2b,2b+1}: v[b],q[b] L2-resident
  int slot = bid >> 3;                   // 0..63 within XCD
  int b    = xcd >> 1;
  int m0   = 32 * (slot + 64 * (xcd & 1));   // 128 m-tiles/batch
  int tid  = threadIdx.x;
  int w    = tid >> 6;                   // 0..15
  int lane = tid & 63;
  int l15  = lane & 15, lg = lane >> 4;
  int wk   = w >> 3, wc = w & 7;

  __shared__ __align__(16) unsigned short P_lds[2][32][256];  // 32 KB
  __shared__ float dpart[16][32];
  __shared__ float denom_s[32];

  const _Float16*       qb    = qh + (size_t)b * Nsp * 32;
  const _Float16*       kb    = kh + (size_t)b * Nsp * 32;
  const unsigned short* vbase = vb + (size_t)b * Cch * Nsp;

  // K B-frags resident: frag j covers m = m0+16j
  half8 kB[2];
#pragma unroll
  for (int j = 0; j < 2; ++j)
    kB[j] = *(const half8*)(kb + (size_t)(m0 + 16 * j + l15) * 32 + lg * 8);

  f32x4 acc[2][2];   // [c16][j(m16)] — partial over this wave's n-half
#pragma unroll
  for (int i = 0; i < 2; ++i)
#pragma unroll
    for (int j = 0; j < 2; ++j) { acc[i][j][0]=0.f; acc[i][j][1]=0.f; acc[i][j][2]=0.f; acc[i][j][3]=0.f; }

  float dsum[2] = {0.f, 0.f};

  const _Float16*       qp  = qb + (size_t)(16 * w + l15) * 32 + lg * 8;   // +256*32 halves/iter
  const unsigned short* pv0 = vbase + (size_t)(32 * wc + l15) * Nsp + 128 * wk + lg * 8;
  const unsigned short* pv1 = pv0 + (size_t)16 * Nsp;
  int xorh  = 8 * (l15 & 7);
  int wcol  = (16 * w + 4 * lg) ^ xorh;
  int rbase = 128 * wk + 8 * lg;

  for (int it = 0; it < 16; ++it) {
    int buf = it & 1;
    // ---- QK^T for this wave's 16-n slice x m32
    half8 qA = *(const half8*)qp;  qp += 256 * 32;
    f32x4 S[2];
#pragma unroll
    for (int j = 0; j < 2; ++j) {
      f32x4 z; z[0]=0.f; z[1]=0.f; z[2]=0.f; z[3]=0.f;
      S[j] = __builtin_amdgcn_mfma_f32_16x16x32_f16(qA, kB[j], z, 0, 0, 0);
    }
    ushort4v pb[2];
#pragma unroll
    for (int j = 0; j < 2; ++j) {
#pragma unroll
      for (int r = 0; r < 4; ++r) {
        float p = exp2f(fmaf(S[j][r], LOG2E, NSHIFT));
        dsum[j] += p;
        pb[j][r] = f2bf(p);
      }
    }
#pragma unroll
    for (int j = 0; j < 2; ++j)
      *(ushort4v*)&P_lds[buf][16 * j + l15][wcol] = pb[j];
    __syncthreads();   // single barrier/iter: dbuf makes write(t+1) vs read(t) race-free
    // ---- PV: c-stripe 32*wc x n-half 128*wk
    __builtin_amdgcn_s_setprio(1);
#pragma unroll
    for (int k = 0; k < 4; ++k) {
      short8_t aV0 = *(const short8_t*)(pv0 + 32 * k);
      short8_t aV1 = *(const short8_t*)(pv1 + 32 * k);
      int rc = (rbase + 32 * k) ^ xorh;
      short8_t bP0 = *(const short8_t*)&P_lds[buf][l15][rc];
      short8_t bP1 = *(const short8_t*)&P_lds[buf][16 + l15][rc];
      acc[0][0] = __builtin_amdgcn_mfma_f32_16x16x32_bf16(aV0, bP0, acc[0][0], 0, 0, 0);
      acc[0][1] = __builtin_amdgcn_mfma_f32_16x16x32_bf16(aV0, bP1, acc[0][1], 0, 0, 0);
      acc[1][0] = __builtin_amdgcn_mfma_f32_16x16x32_bf16(aV1, bP0, acc[1][0], 0, 0, 0);
      acc[1][1] = __builtin_amdgcn_mfma_f32_16x16x32_bf16(aV1, bP1, acc[1][1], 0, 0, 0);
    }
    __builtin_amdgcn_s_setprio(0);
    pv0 += 256; pv1 += 256;
  }

  // ---- denominator partials (per wave, per j)
#pragma unroll
  for (int j = 0; j < 2; ++j) {
    float d = dsum[j];
    d += __shfl_xor(d, 16);
    d += __shfl_xor(d, 32);
    dsum[j] = d;
  }
  if (lane < 16) {
#pragma unroll
    for (int j = 0; j < 2; ++j) dpart[w][16 * j + lane] = dsum[j];
  }
  __syncthreads();   // all waves past loop; P_lds reusable
  if (tid < 32) {
    float s = 0.f;
#pragma unroll
    for (int ww = 0; ww < 16; ++ww) s += dpart[ww][tid];
    denom_s[tid] = s;
  }
  // ---- merge wk=1 partials into wk=0 via LDS (reuse P_lds as f32; 32 KB = 8192 floats)
  float* mbuf = (float*)P_lds;
  if (w >= 8) {
#pragma unroll
    for (int c16 = 0; c16 < 2; ++c16)
#pragma unroll
      for (int j = 0; j < 2; ++j)
#pragma unroll
        for (int r = 0; r < 4; ++r)
          mbuf[lane + 64 * (((c16 * 2 + j) * 4 + r) + 16 * (w - 8))] = acc[c16][j][r];
  }
  __syncthreads();
  if (w < 8) {
    float g = gamma[0];
#pragma unroll
    for (int c16 = 0; c16 < 2; ++c16) {
#pragma unroll
      for (int j = 0; j < 2; ++j) {
        float dn = denom_s[16 * j + l15];
#pragma unroll
        for (int r = 0; r < 4; ++r) {
          float a = acc[c16][j][r] + mbuf[lane + 64 * (((c16 * 2 + j) * 4 + r) + 16 * w)];
          int c = 32 * w + 16 * c16 + 4 * lg + r;
          int m = m0 + 16 * j + l15;
          size_t idx = ((size_t)b * Cch + c) * Nsp + m;
          out[idx] = g * (a / dn) + x[idx];
        }
      }
    }
  }
}

extern "C" void kernel_launch(void* const* d_in, const int* in_sizes, int n_in,
                              void* d_out, int out_size, void* d_ws, size_t ws_size,
                              hipStream_t stream) {
  const float* x     = (const float*)d_in[0];
  const float* wq    = (const float*)d_in[1];
  const float* bq    = (const float*)d_in[2];
  const float* wk    = (const float*)d_in[3];
  const float* bk    = (const float*)d_in[4];
  const float* wv    = (const float*)d_in[5];
  const float* bv    = (const float*)d_in[6];
  const float* gamma = (const float*)d_in[7];
  float* out = (float*)d_out;

  char* ws = (char*)d_ws;
  _Float16*       qh   = (_Float16*)ws;                        // 1 MB
  _Float16*       kh   = (_Float16*)(ws + (1u << 20));         // 1 MB
  unsigned short* vb   = (unsigned short*)(ws + (2u << 20));   // 8 MB
  _Float16*       Wh   = (_Float16*)(ws + (10u << 20));        // 160 KB
  float*          bias = (float*)(ws + (10u << 20) + (320u * 256u * 2u));

  wconv_kernel<<<dim3(80), dim3(256), 0, stream>>>(wq, wk, wv, bq, bk, bv, Wh, bias);
  proj_kernel<<<dim3(512), dim3(256), 0, stream>>>(x, Wh, bias, qh, kh, vb);
  attn_kernel<<<dim3(512), dim3(1024), 0, stream>>>(qh, kh, vb, x, gamma, out);
}

// Round 13
// 121.246 us; speedup vs baseline: 1.4914x; 1.4914x over previous
//
#include <hip/hip_runtime.h>

#define Bsz 4
#define Cch 256
#define Nsp 4096
#define XT_STRIDE 264   // proj LDS stride (halves)

typedef _Float16 half8 __attribute__((ext_vector_type(8)));
typedef _Float16 half4v __attribute__((ext_vector_type(4)));
typedef short short8_t __attribute__((ext_vector_type(8)));
typedef float f32x4 __attribute__((ext_vector_type(4)));
typedef float fl4 __attribute__((ext_vector_type(4)));
typedef unsigned short ushort4v __attribute__((ext_vector_type(4)));

#define LOG2E 1.4426950408889634f
#define NSHIFT (-28.853900817779268f)   // -20 * log2(e)

static __device__ __forceinline__ unsigned short f2bf(float f) {
  unsigned u = __builtin_bit_cast(unsigned, f);
  u += 0x7FFFu + ((u >> 16) & 1u);      // RTNE
  return (unsigned short)(u >> 16);
}

// ---------------- W/bias pre-convert: wq|wk|wv -> Wh f16 [320][256], bias f32 [320]
__global__ __launch_bounds__(256) void wconv_kernel(
    const float* __restrict__ wq, const float* __restrict__ wk, const float* __restrict__ wv,
    const float* __restrict__ bq, const float* __restrict__ bk, const float* __restrict__ bv,
    _Float16* __restrict__ Wh, float* __restrict__ bias)
{
  int t = blockIdx.x * 256 + threadIdx.x;
  int idx0 = t * 4;
  int o = idx0 >> 8, c = idx0 & 255;
  const float* src = (o < 32) ? (wq + o * 256)
                   : (o < 64) ? (wk + (o - 32) * 256)
                              : (wv + (o - 64) * 256);
  fl4 w4 = *(const fl4*)(src + c);
  half4v h;
#pragma unroll
  for (int j = 0; j < 4; ++j) h[j] = (_Float16)w4[j];
  *(half4v*)(Wh + idx0) = h;
  if (t < 320) bias[t] = (t < 32) ? bq[t] : (t < 64) ? bk[t - 32] : bv[t - 64];
}

// ---------------- Projection GEMM: out[o, n] = Wh[o,:] . x[b,:,n] + bias
// Coalesced staging: each thread reads float4 along n (8-lane groups = 128 B runs).
__global__ __launch_bounds__(256) void proj_kernel(
    const float* __restrict__ x, const _Float16* __restrict__ Wh,
    const float* __restrict__ bias,
    _Float16* __restrict__ qh, _Float16* __restrict__ kh,
    unsigned short* __restrict__ vbuf)
{
  int bid = blockIdx.x;          // 512 = b(4) x nt(128)
  int nt  = bid & 127;
  int b   = bid >> 7;
  int n0  = nt * 32;
  int tid = threadIdx.x;
  int w   = tid >> 6, lane = tid & 63;
  int l15 = lane & 15, lg = lane >> 4;

  __shared__ __align__(16) _Float16 xT[32 * XT_STRIDE];

  const float* xb = x + (size_t)b * Cch * Nsp + n0;

  {
    int cq = tid >> 3;          // 0..31
    int nq = (tid & 7) * 4;     // n quad
#pragma unroll
    for (int p = 0; p < 8; ++p) {
      int c = p * 32 + cq;
      fl4 v = *(const fl4*)(xb + (size_t)c * Nsp + nq);
#pragma unroll
      for (int i = 0; i < 4; ++i)
        xT[(nq + i) * XT_STRIDE + c] = (_Float16)v[i];
    }
  }
  __syncthreads();

  int nsub = (w & 1) * 16;
  half8 bX[8];
#pragma unroll
  for (int k = 0; k < 8; ++k)
    bX[k] = *(const half8*)&xT[(nsub + l15) * XT_STRIDE + k * 32 + lg * 8];

  int n = n0 + nsub + l15;
  int ot0 = (w >> 1) * 10;
#pragma unroll
  for (int t = 0; t < 10; ++t) {
    int ot = ot0 + t;
    const _Float16* wrow = Wh + (size_t)(ot * 16 + l15) * 256 + lg * 8;
    f32x4 acc; acc[0]=0.f; acc[1]=0.f; acc[2]=0.f; acc[3]=0.f;
#pragma unroll
    for (int k = 0; k < 8; ++k) {
      half8 aW = *(const half8*)(wrow + k * 32);
      acc = __builtin_amdgcn_mfma_f32_16x16x32_f16(aW, bX[k], acc, 0, 0, 0);
    }
    fl4 bs = *(const fl4*)(bias + ot * 16 + lg * 4);
    if (ot < 2) {
      half4v qv;
#pragma unroll
      for (int r = 0; r < 4; ++r) qv[r] = (_Float16)(acc[r] + bs[r]);
      *(half4v*)(qh + ((size_t)b * Nsp + n) * 32 + ot * 16 + lg * 4) = qv;
    } else if (ot < 4) {
      half4v kv;
#pragma unroll
      for (int r = 0; r < 4; ++r) kv[r] = (_Float16)(acc[r] + bs[r]);
      *(half4v*)(kh + ((size_t)b * Nsp + n) * 32 + (ot - 2) * 16 + lg * 4) = kv;
    } else {
      int cv = (ot - 4) * 16 + lg * 4;
#pragma unroll
      for (int r = 0; r < 4; ++r)
        vbuf[((size_t)b * Cch + cv + r) * Nsp + n] = f2bf(acc[r] + bs[r]);
    }
  }
}

// ---------------- Fused attention: EXACT r5 structure (best measured: 89.6 us).
// 256 blocks x 1024 thr (16 waves), 1 block/CU, n-step 256, m-tile 64.
// QK: wave w owns n-slice [n0+16w,+16). PV: wave (wk=w>>3, wc=w&7): c-stripe
// 32*wc, n-half 128*wk; V read exactly once per block. Partial acc merged via
// LDS at end (additive, fixed-shift softmax). Single barrier per iter (P dbuf).
// Only delta vs r5: __expf -> exp2f(fma) (one less VALU op per element).
__global__ __launch_bounds__(1024) void attn_kernel(
    const _Float16* __restrict__ qh, const _Float16* __restrict__ kh,
    const unsigned short* __restrict__ vb, const float* __restrict__ x,
    const float* __restrict__ gamma, float* __restrict__ out)
{
  int bid  = blockIdx.x;                 // 256 blocks, 1/CU
  int xcd  = bid & 7;                    // batch b -> XCDs {2b,2b+1}: v[b] L2-resident
  int slot = bid >> 3;
  int b    = xcd >> 1;
  int mt   = slot + 32 * (xcd & 1);
  int m0   = mt * 64;
  int tid  = threadIdx.x;
  int w    = tid >> 6;                   // 0..15
  int lane = tid & 63;
  int l15  = lane & 15, lg = lane >> 4;
  int wk   = w >> 3, wc = w & 7;

  __shared__ __align__(16) unsigned short P_lds[2][64][256];  // 64 KB
  __shared__ float dpart[16][64];
  __shared__ float denom_s[64];

  const _Float16*       qb    = qh + (size_t)b * Nsp * 32;
  const _Float16*       kb    = kh + (size_t)b * Nsp * 32;
  const unsigned short* vbase = vb + (size_t)b * Cch * Nsp;

  half8 kB[4];
#pragma unroll
  for (int j = 0; j < 4; ++j)
    kB[j] = *(const half8*)(kb + (size_t)(m0 + 16 * j + l15) * 32 + lg * 8);

  f32x4 acc[2][4];   // [c16][j]  (partial over this wave's n-half)
#pragma unroll
  for (int i = 0; i < 2; ++i)
#pragma unroll
    for (int j = 0; j < 4; ++j) { acc[i][j][0]=0.f; acc[i][j][1]=0.f; acc[i][j][2]=0.f; acc[i][j][3]=0.f; }

  float dsum[4] = {0.f, 0.f, 0.f, 0.f};

  const _Float16*       qp  = qb + (size_t)(16 * w + l15) * 32 + lg * 8;         // +8192/iter
  const unsigned short* pv0 = vbase + (size_t)(32 * wc + l15) * Nsp + 128 * wk + lg * 8;
  const unsigned short* pv1 = pv0 + (size_t)16 * Nsp;
  int xorh  = 8 * (l15 & 7);
  int wcol  = (16 * w + 4 * lg) ^ xorh;
  int rbase = 128 * wk + 8 * lg;

  for (int it = 0; it < 16; ++it) {
    int buf = it & 1;
    // ---- QK^T for this wave's 16-n slice
    half8 qA = *(const half8*)qp;  qp += 256 * 32;
    f32x4 S[4];
#pragma unroll
    for (int j = 0; j < 4; ++j) {
      f32x4 z; z[0]=0.f; z[1]=0.f; z[2]=0.f; z[3]=0.f;
      S[j] = __builtin_amdgcn_mfma_f32_16x16x32_f16(qA, kB[j], z, 0, 0, 0);
    }
    ushort4v pb[4];
#pragma unroll
    for (int j = 0; j < 4; ++j) {
#pragma unroll
      for (int r = 0; r < 4; ++r) {
        float p = exp2f(fmaf(S[j][r], LOG2E, NSHIFT));
        dsum[j] += p;
        pb[j][r] = f2bf(p);
      }
    }
#pragma unroll
    for (int j = 0; j < 4; ++j)
      *(ushort4v*)&P_lds[buf][16 * j + l15][wcol] = pb[j];
    __syncthreads();   // P[buf] visible; prev buf's readers already passed last barrier
    // ---- PV: this wave's (32c stripe) x (128n half), full 64 m
    const unsigned short* pk0 = pv0;
    const unsigned short* pk1 = pv1;
    __builtin_amdgcn_s_setprio(1);
#pragma unroll
    for (int k = 0; k < 4; ++k) {
      short8_t aV0 = *(const short8_t*)pk0;
      short8_t aV1 = *(const short8_t*)pk1;
      pk0 += 32; pk1 += 32;
#pragma unroll
      for (int j = 0; j < 4; ++j) {
        int rc = (rbase + 32 * k) ^ xorh;
        short8_t bP = *(const short8_t*)&P_lds[buf][16 * j + l15][rc];
        acc[0][j] = __builtin_amdgcn_mfma_f32_16x16x32_bf16(aV0, bP, acc[0][j], 0, 0, 0);
        acc[1][j] = __builtin_amdgcn_mfma_f32_16x16x32_bf16(aV1, bP, acc[1][j], 0, 0, 0);
      }
    }
    __builtin_amdgcn_s_setprio(0);
    pv0 += 256; pv1 += 256;
  }

  // ---- denominator partials
#pragma unroll
  for (int j = 0; j < 4; ++j) {
    float d = dsum[j];
    d += __shfl_xor(d, 16);
    d += __shfl_xor(d, 32);
    dsum[j] = d;
  }
  if (lane < 16) {
#pragma unroll
    for (int j = 0; j < 4; ++j) dpart[w][16 * j + lane] = dsum[j];
  }
  __syncthreads();   // dpart ready; all PV done -> P_lds reusable
  if (tid < 64) {
    float s = 0.f;
#pragma unroll
    for (int ww = 0; ww < 16; ++ww) s += dpart[ww][tid];
    denom_s[tid] = s;
  }
  // ---- merge wk=1 partial acc into wk=0 via LDS (reuse P_lds as f32 buffer)
  float* mbuf = (float*)P_lds;
  if (w >= 8) {
#pragma unroll
    for (int c16 = 0; c16 < 2; ++c16)
#pragma unroll
      for (int j = 0; j < 4; ++j)
#pragma unroll
        for (int r = 0; r < 4; ++r)
          mbuf[lane + 64 * (((c16 * 4 + j) * 4 + r) + 32 * (w - 8))] = acc[c16][j][r];
  }
  __syncthreads();
  if (w < 8) {
    float g = gamma[0];
#pragma unroll
    for (int c16 = 0; c16 < 2; ++c16) {
#pragma unroll
      for (int j = 0; j < 4; ++j) {
        float dn = denom_s[16 * j + l15];
#pragma unroll
        for (int r = 0; r < 4; ++r) {
          float a = acc[c16][j][r] + mbuf[lane + 64 * (((c16 * 4 + j) * 4 + r) + 32 * w)];
          int c = 32 * w + 16 * c16 + 4 * lg + r;
          int m = m0 + 16 * j + l15;
          size_t idx = ((size_t)b * Cch + c) * Nsp + m;
          out[idx] = g * (a / dn) + x[idx];
        }
      }
    }
  }
}

extern "C" void kernel_launch(void* const* d_in, const int* in_sizes, int n_in,
                              void* d_out, int out_size, void* d_ws, size_t ws_size,
                              hipStream_t stream) {
  const float* x     = (const float*)d_in[0];
  const float* wq    = (const float*)d_in[1];
  const float* bq    = (const float*)d_in[2];
  const float* wk    = (const float*)d_in[3];
  const float* bk    = (const float*)d_in[4];
  const float* wv    = (const float*)d_in[5];
  const float* bv    = (const float*)d_in[6];
  const float* gamma = (const float*)d_in[7];
  float* out = (float*)d_out;

  char* ws = (char*)d_ws;
  _Float16*       qh   = (_Float16*)ws;                        // 1 MB
  _Float16*       kh   = (_Float16*)(ws + (1u << 20));         // 1 MB
  unsigned short* vb   = (unsigned short*)(ws + (2u << 20));   // 8 MB
  _Float16*       Wh   = (_Float16*)(ws + (10u << 20));        // 160 KB
  float*          bias = (float*)(ws + (10u << 20) + (320u * 256u * 2u));

  wconv_kernel<<<dim3(80), dim3(256), 0, stream>>>(wq, wk, wv, bq, bk, bv, Wh, bias);
  proj_kernel<<<dim3(512), dim3(256), 0, stream>>>(x, Wh, bias, qh, kh, vb);
  attn_kernel<<<dim3(256), dim3(1024), 0, stream>>>(qh, kh, vb, x, gamma, out);
}